// Round 2
// baseline (5718.397 us; speedup 1.0000x reference)
//
#include <hip/hip_runtime.h>
#include <math.h>

#define HW 4096   // 64*64

// ---------------------------------------------------------------------------
// Implicit-GEMM 3x3 SAME conv over two sources (x_t and h_{t-1}), accumulating
// z[pos][n] = sum_taps sum_cin x*Wx + h*Wh   (bias added in gate kernel).
// Tile: BM=128 positions (2 image rows of one batch), BN=64 out channels,
// BK=32 input channels. 256 threads, 8x4 per-thread tile (VALU-bound).
// ---------------------------------------------------------------------------
__device__ inline void fma4(float4& d, float s, const float4& v) {
    d.x = fmaf(s, v.x, d.x);
    d.y = fmaf(s, v.y, d.y);
    d.z = fmaf(s, v.z, d.z);
    d.w = fmaf(s, v.w, d.w);
}

__global__ __launch_bounds__(256, 2) void conv_gemm(
    const float* __restrict__ X, long xBStride, int Cx,
    const float* __restrict__ Hs, int F,
    const float* __restrict__ Wx, const float* __restrict__ Wh,
    float* __restrict__ Z, int N)
{
    __shared__ float As[128][36];   // positions x cin-chunk (pitch 36)
    __shared__ float Bs[32][72];    // cin-chunk x cout tile (pitch 72)

    const int tid = threadIdx.x;
    const int tx  = tid & 15;       // out-channel group (4 ch each)
    const int ty  = tid >> 4;       // position sub-index
    const int bx  = blockIdx.x;     // b*32 + row-pair
    const int b   = bx >> 5;
    const int y0  = (bx & 31) << 1; // first of 2 rows
    const int n0  = blockIdx.y << 6;

    float4 acc[8];
    #pragma unroll
    for (int i = 0; i < 8; ++i) acc[i] = make_float4(0.f, 0.f, 0.f, 0.f);

    #pragma unroll 1
    for (int src = 0; src < 2; ++src) {
        const float* S  = src ? Hs : X;
        const int    C  = src ? F : Cx;
        const long   bs = src ? (long)HW * F : xBStride;
        const float* Wt = src ? Wh : Wx;
        const float* Sb = S + (long)b * bs;

        #pragma unroll 1
        for (int ky = 0; ky < 3; ++ky) {
            #pragma unroll 1
            for (int kx = 0; kx < 3; ++kx) {
                const float* Wtap = Wt + (long)((ky * 3 + kx) * C) * N + n0;
                #pragma unroll 1
                for (int c0 = 0; c0 < C; c0 += 32) {
                    // ---- global loads to registers (no LDS touched yet) ----
                    float4 av[4];
                    #pragma unroll
                    for (int s = 0; s < 4; ++s) {
                        int slot = tid + (s << 8);      // 0..1023
                        int p  = slot >> 3;             // position 0..127
                        int cg = slot & 7;              // float4 group in chunk
                        int yy = y0 + (p >> 6) + ky - 1;
                        int xx = (p & 63) + kx - 1;
                        av[s] = make_float4(0.f, 0.f, 0.f, 0.f);
                        if ((unsigned)yy < 64u && (unsigned)xx < 64u)
                            av[s] = *(const float4*)(Sb + (long)((yy << 6) | xx) * C
                                                     + c0 + (cg << 2));
                    }
                    float4 bv[2];
                    #pragma unroll
                    for (int s = 0; s < 2; ++s) {
                        int slot = tid + (s << 8);      // 0..511
                        int c  = slot >> 4;             // cin 0..31 within chunk
                        int ng = slot & 15;             // cout float4 group
                        bv[s] = *(const float4*)(Wtap + (long)(c0 + c) * N + (ng << 2));
                    }
                    __syncthreads();    // previous chunk's compute done
                    #pragma unroll
                    for (int s = 0; s < 4; ++s) {
                        int slot = tid + (s << 8);
                        int p = slot >> 3, cg = slot & 7;
                        *(float4*)&As[p][cg << 2] = av[s];
                    }
                    #pragma unroll
                    for (int s = 0; s < 2; ++s) {
                        int slot = tid + (s << 8);
                        int c = slot >> 4, ng = slot & 15;
                        *(float4*)&Bs[c][ng << 2] = bv[s];
                    }
                    __syncthreads();
                    // ---- FMA over the 32-deep K chunk ----
                    #pragma unroll
                    for (int kq = 0; kq < 8; ++kq) {
                        float4 b0 = *(const float4*)&Bs[(kq << 2) + 0][tx << 2];
                        float4 b1 = *(const float4*)&Bs[(kq << 2) + 1][tx << 2];
                        float4 b2 = *(const float4*)&Bs[(kq << 2) + 2][tx << 2];
                        float4 b3 = *(const float4*)&Bs[(kq << 2) + 3][tx << 2];
                        #pragma unroll
                        for (int i = 0; i < 8; ++i) {
                            float4 a = *(const float4*)&As[(i << 4) + ty][kq << 2];
                            fma4(acc[i], a.x, b0);
                            fma4(acc[i], a.y, b1);
                            fma4(acc[i], a.z, b2);
                            fma4(acc[i], a.w, b3);
                        }
                    }
                }
            }
        }
    }

    // ---- epilogue: write z ----
    #pragma unroll
    for (int i = 0; i < 8; ++i) {
        int p = (i << 4) + ty;                  // position within tile
        int y = y0 + (p >> 6), x = p & 63;
        float* dst = Z + (long)(((b << 6) | y) << 6 | x) * N + n0 + (tx << 2);
        *(float4*)dst = acc[i];
    }
}

// ---------------------------------------------------------------------------
// Pointwise LSTM gate update. z -> (i,f,g,o) -> c,h update; writes h (state)
// and relu(h) (sequence output). Memory-bound.
// ---------------------------------------------------------------------------
__device__ inline float hsig(float x) {
    return fminf(fmaxf(0.2f * x + 0.5f, 0.f), 1.f);
}

__global__ __launch_bounds__(256) void lstm_gates(
    const float* __restrict__ Z, const float* __restrict__ bias,
    float* __restrict__ Cst, float* __restrict__ Hst,
    float* __restrict__ Out, long outBStride, int F, int N, int lg_nf4)
{
    int t4  = blockIdx.x * 256 + threadIdx.x;
    int nf4m = (1 << lg_nf4) - 1;
    int f0  = (t4 & nf4m) << 2;
    int pos = t4 >> lg_nf4;            // b*4096 + p
    int b   = pos >> 12;
    int p   = pos & 4095;

    const float* zp = Z + (long)pos * N;
    float4 zi = *(const float4*)(zp + f0);
    float4 zf = *(const float4*)(zp + F + f0);
    float4 zg = *(const float4*)(zp + 2 * F + f0);
    float4 zo = *(const float4*)(zp + 3 * F + f0);
    float4 bi = *(const float4*)(bias + f0);
    float4 bf = *(const float4*)(bias + F + f0);
    float4 bg = *(const float4*)(bias + 2 * F + f0);
    float4 bo = *(const float4*)(bias + 3 * F + f0);
    float4 c  = *(const float4*)(Cst + (long)pos * F + f0);
    float4 hv, ov4;

#define GATE(comp) { \
        float iv = hsig(zi.comp + bi.comp); \
        float fv = hsig(zf.comp + bf.comp); \
        float gv = tanhf(zg.comp + bg.comp); \
        float og = hsig(zo.comp + bo.comp); \
        float cn = fv * c.comp + iv * gv; \
        float hn = og * tanhf(cn); \
        c.comp = cn; hv.comp = hn; ov4.comp = fmaxf(hn, 0.f); }
    GATE(x) GATE(y) GATE(z) GATE(w)
#undef GATE

    *(float4*)(Cst + (long)pos * F + f0) = c;
    *(float4*)(Hst + (long)pos * F + f0) = hv;
    *(float4*)(Out + (long)b * outBStride + (long)p * F + f0) = ov4;
}

// ---------------------------------------------------------------------------
// Host: 3 layers x 16 timesteps. d_out doubles as the layer-1 sequence buffer
// (layout [T,B,H,W,64]); it is dead by the time layer 3 overwrites d_out with
// the final [B,T,H,W,64] output. Workspace: seq2 + h + c + z = ~59 MB.
// ---------------------------------------------------------------------------
extern "C" void kernel_launch(void* const* d_in, const int* in_sizes, int n_in,
                              void* d_out, int out_size, void* d_ws, size_t ws_size,
                              hipStream_t stream)
{
    const float* x   = (const float*)d_in[0];
    const float* Wx1 = (const float*)d_in[1];
    const float* Wh1 = (const float*)d_in[2];
    const float* b1  = (const float*)d_in[3];
    const float* Wx2 = (const float*)d_in[4];
    const float* Wh2 = (const float*)d_in[5];
    const float* b2  = (const float*)d_in[6];
    const float* Wx3 = (const float*)d_in[7];
    const float* Wh3 = (const float*)d_in[8];
    const float* b3  = (const float*)d_in[9];
    float* out = (float*)d_out;
    float* ws  = (float*)d_ws;

    const int T = 16, B = 4;
    float* seq2 = ws;                   // 16*4*4096*32 = 8388608 floats
    float* hbuf = ws + 8388608;         // 1048576 floats (max F=64)
    float* cbuf = ws + 9437184;         // 1048576 floats
    float* zbuf = ws + 10485760;        // 4*4096*256 = 4194304 floats
    // total: 14,680,064 floats = 58.7 MB of d_ws

    struct L {
        const float *Wx, *Wh, *bias; int Cx, F;
        const float* in0; long inT, inB;
        float* out0; long outT, outB;
    };
    L ls[3] = {
        { Wx1, Wh1, b1, 64, 64, x,    (long)HW * 64, (long)T * HW * 64,
          out,  (long)B * HW * 64, (long)HW * 64 },
        { Wx2, Wh2, b2, 64, 32, out,  (long)B * HW * 64, (long)HW * 64,
          seq2, (long)B * HW * 32, (long)HW * 32 },
        { Wx3, Wh3, b3, 32, 64, seq2, (long)B * HW * 32, (long)HW * 32,
          out,  (long)HW * 64, (long)T * HW * 64 },
    };

    for (int l = 0; l < 3; ++l) {
        const L& P = ls[l];
        int N = 4 * P.F;
        hipMemsetAsync(hbuf, 0, (size_t)B * HW * P.F * sizeof(float), stream);
        hipMemsetAsync(cbuf, 0, (size_t)B * HW * P.F * sizeof(float), stream);
        int lg_nf4 = (P.F == 64) ? 4 : 3;
        int gthreads = B * HW * (P.F / 4);
        for (int t = 0; t < T; ++t) {
            conv_gemm<<<dim3(B * 32, N / 64), 256, 0, stream>>>(
                P.in0 + (long)t * P.inT, P.inB, P.Cx, hbuf, P.F,
                P.Wx, P.Wh, zbuf, N);
            lstm_gates<<<gthreads / 256, 256, 0, stream>>>(
                zbuf, P.bias, cbuf, hbuf,
                P.out0 + (long)t * P.outT, P.outB, P.F, N, lg_nf4);
        }
    }
}

// Round 3
// 2250.870 us; speedup vs baseline: 2.5405x; 2.5405x over previous
//
#include <hip/hip_runtime.h>
#include <math.h>

#define HW 4096   // 64*64

// ---------------------------------------------------------------------------
// bf16 hi/lo split helpers (explicit bit ops, RN rounding)
// ---------------------------------------------------------------------------
__device__ __host__ inline unsigned short f2bf(float f) {
    unsigned u = __float_as_uint(f);
    unsigned r = (u + 0x7FFFu + ((u >> 16) & 1u)) >> 16;
    return (unsigned short)r;
}
__device__ inline float bf2f(unsigned short h) {
    return __uint_as_float(((unsigned)h) << 16);
}

typedef __attribute__((ext_vector_type(8))) short short8;   // bf16x8 MFMA frag
typedef __attribute__((ext_vector_type(4))) float f32x4;    // MFMA acc frag

// ---------------------------------------------------------------------------
// Weight pre-split: W [tap*C][N] fp32 (HWIO) -> Wt_hi/Wt_lo [tap][N][C] bf16.
// Transposed so B-fragments are k-contiguous ds_read_b128.
// ---------------------------------------------------------------------------
__global__ __launch_bounds__(256) void wsplit(
    const float* __restrict__ W, int C, int N,
    unsigned short* __restrict__ Wh_, unsigned short* __restrict__ Wl_)
{
    int i = blockIdx.x * 256 + threadIdx.x;
    int total = 9 * C * N;
    if (i >= total) return;
    int n = i % N;
    int rc = i / N;
    int tap = rc / C, c = rc % C;
    float v = W[i];
    unsigned short h = f2bf(v);
    unsigned short l = f2bf(v - bf2f(h));
    long o = (long)(tap * N + n) * C + c;
    Wh_[o] = h; Wl_[o] = l;
}

// ---------------------------------------------------------------------------
// MFMA implicit-GEMM 3x3 SAME conv over x_t and h_{t-1}.
// z[m][n] = sum_src sum_tap sum_c  A*W,  A split hi/lo bf16 inline at staging,
// 3-term MFMA (hi*hi + hi*lo + lo*hi) for fp32-like accuracy.
// Tile: BM=64 positions (one image row), BN=128, BK=32. 256 threads / 4 waves,
// wave w owns 64m x 32n (4x2 fragments of 16x16, 24 MFMAs per K-chunk).
// ---------------------------------------------------------------------------
__global__ __launch_bounds__(256, 2) void conv_mfma(
    const float* __restrict__ X, long xBStride, int Cx,
    const float* __restrict__ Hs, int F,
    const unsigned short* __restrict__ Wxh, const unsigned short* __restrict__ Wxl,
    const unsigned short* __restrict__ Whh, const unsigned short* __restrict__ Whl,
    float* __restrict__ Z, int N)
{
    __shared__ unsigned short Ah[64][40], Al[64][40];    // pos x k (pitch 40)
    __shared__ unsigned short Bh[128][40], Bl[128][40];  // n  x k (pitch 40)

    const int tid  = threadIdx.x;
    const int lane = tid & 63;
    const int w    = tid >> 6;
    const int m0   = blockIdx.x << 6;       // 64 positions per block
    const int n0   = blockIdx.y << 7;       // 128 out-channels per block
    const int b    = m0 >> 12;              // batch
    const int y    = (m0 & 4095) >> 6;      // image row (BM == one row)

    // A-staging assignment: thread -> (position, 8-channel group)
    const int ap  = tid >> 2;               // position 0..63 (== x col)
    const int acg = (tid & 3) << 3;         // channel offset 0,8,16,24

    // fragment read offsets
    const int frow = lane & 15;
    const int fk   = (lane >> 4) << 3;
    const int noff = w << 5;                // wave's 32-col slice of B tile

    f32x4 acc[4][2] = {};

    #pragma unroll 1
    for (int src = 0; src < 2; ++src) {
        const float* S  = src ? Hs : X;
        const int    C  = src ? F : Cx;
        const long   bs = src ? (long)HW * F : xBStride;
        const unsigned short* Wth = src ? Whh : Wxh;
        const unsigned short* Wtl = src ? Whl : Wxl;
        const float* Sb = S + (long)b * bs;

        #pragma unroll 1
        for (int ky = 0; ky < 3; ++ky) {
            const int yy = y + ky - 1;
            if ((unsigned)yy >= 64u) continue;   // block-uniform: safe skip
            #pragma unroll 1
            for (int kx = 0; kx < 3; ++kx) {
                const int xx = ap + kx - 1;
                const bool av = (unsigned)xx < 64u;
                const float* Arow = Sb + ((long)(yy << 6) + xx) * C;
                const int tap = ky * 3 + kx;
                #pragma unroll 1
                for (int c0 = 0; c0 < C; c0 += 32) {
                    // ---- preload A: 8 fp32 (zero outside image) ----
                    float4 a0 = make_float4(0.f, 0.f, 0.f, 0.f);
                    float4 a1 = make_float4(0.f, 0.f, 0.f, 0.f);
                    if (av) {
                        a0 = *(const float4*)(Arow + c0 + acg);
                        a1 = *(const float4*)(Arow + c0 + acg + 4);
                    }
                    // ---- preload B: 2 slots x (hi,lo) 16B each ----
                    const int bn0 = tid >> 2;            // n row 0..63
                    const int bkg = (tid & 3) << 3;      // k offset
                    const long wo0 = (long)(tap * N + n0 + bn0) * C + c0 + bkg;
                    const long wo1 = (long)(tap * N + n0 + bn0 + 64) * C + c0 + bkg;
                    uint4 vbh0 = *(const uint4*)(Wth + wo0);
                    uint4 vbl0 = *(const uint4*)(Wtl + wo0);
                    uint4 vbh1 = *(const uint4*)(Wth + wo1);
                    uint4 vbl1 = *(const uint4*)(Wtl + wo1);

                    // ---- split A into hi/lo bf16 ----
                    float v[8] = {a0.x, a0.y, a0.z, a0.w, a1.x, a1.y, a1.z, a1.w};
                    unsigned hw_[4], lw_[4];
                    #pragma unroll
                    for (int j = 0; j < 4; ++j) {
                        unsigned short h0 = f2bf(v[2*j]);
                        unsigned short h1 = f2bf(v[2*j+1]);
                        unsigned short l0 = f2bf(v[2*j]   - bf2f(h0));
                        unsigned short l1 = f2bf(v[2*j+1] - bf2f(h1));
                        hw_[j] = (unsigned)h0 | ((unsigned)h1 << 16);
                        lw_[j] = (unsigned)l0 | ((unsigned)l1 << 16);
                    }

                    __syncthreads();   // previous chunk's readers done
                    *(uint4*)&Ah[ap][acg] = make_uint4(hw_[0], hw_[1], hw_[2], hw_[3]);
                    *(uint4*)&Al[ap][acg] = make_uint4(lw_[0], lw_[1], lw_[2], lw_[3]);
                    *(uint4*)&Bh[bn0][bkg]      = vbh0;
                    *(uint4*)&Bl[bn0][bkg]      = vbl0;
                    *(uint4*)&Bh[bn0 + 64][bkg] = vbh1;
                    *(uint4*)&Bl[bn0 + 64][bkg] = vbl1;
                    __syncthreads();

                    // ---- fragments + 24 MFMAs ----
                    short8 fah[4], fal[4], fbh[2], fbl[2];
                    #pragma unroll
                    for (int mf = 0; mf < 4; ++mf) {
                        fah[mf] = *(const short8*)&Ah[(mf << 4) + frow][fk];
                        fal[mf] = *(const short8*)&Al[(mf << 4) + frow][fk];
                    }
                    #pragma unroll
                    for (int nf = 0; nf < 2; ++nf) {
                        fbh[nf] = *(const short8*)&Bh[noff + (nf << 4) + frow][fk];
                        fbl[nf] = *(const short8*)&Bl[noff + (nf << 4) + frow][fk];
                    }
                    #pragma unroll
                    for (int mf = 0; mf < 4; ++mf)
                        #pragma unroll
                        for (int nf = 0; nf < 2; ++nf) {
                            acc[mf][nf] = __builtin_amdgcn_mfma_f32_16x16x32_bf16(
                                fah[mf], fbh[nf], acc[mf][nf], 0, 0, 0);
                            acc[mf][nf] = __builtin_amdgcn_mfma_f32_16x16x32_bf16(
                                fah[mf], fbl[nf], acc[mf][nf], 0, 0, 0);
                            acc[mf][nf] = __builtin_amdgcn_mfma_f32_16x16x32_bf16(
                                fal[mf], fbh[nf], acc[mf][nf], 0, 0, 0);
                        }
                }
            }
        }
    }

    // ---- epilogue: C/D layout col=lane&15, row=(lane>>4)*4+reg ----
    const int col0  = n0 + noff + (lane & 15);
    const int rbase = m0 + ((lane >> 4) << 2);
    #pragma unroll
    for (int mf = 0; mf < 4; ++mf)
        #pragma unroll
        for (int nf = 0; nf < 2; ++nf)
            #pragma unroll
            for (int r = 0; r < 4; ++r)
                Z[(long)(rbase + (mf << 4) + r) * N + col0 + (nf << 4)] = acc[mf][nf][r];
}

// ---------------------------------------------------------------------------
// Pointwise LSTM gate update (unchanged from round 2).
// ---------------------------------------------------------------------------
__device__ inline float hsig(float x) {
    return fminf(fmaxf(0.2f * x + 0.5f, 0.f), 1.f);
}

__global__ __launch_bounds__(256) void lstm_gates(
    const float* __restrict__ Z, const float* __restrict__ bias,
    float* __restrict__ Cst, float* __restrict__ Hst,
    float* __restrict__ Out, long outBStride, int F, int N, int lg_nf4)
{
    int t4  = blockIdx.x * 256 + threadIdx.x;
    int nf4m = (1 << lg_nf4) - 1;
    int f0  = (t4 & nf4m) << 2;
    int pos = t4 >> lg_nf4;            // b*4096 + p
    int b   = pos >> 12;
    int p   = pos & 4095;

    const float* zp = Z + (long)pos * N;
    float4 zi = *(const float4*)(zp + f0);
    float4 zf = *(const float4*)(zp + F + f0);
    float4 zg = *(const float4*)(zp + 2 * F + f0);
    float4 zo = *(const float4*)(zp + 3 * F + f0);
    float4 bi = *(const float4*)(bias + f0);
    float4 bf = *(const float4*)(bias + F + f0);
    float4 bg = *(const float4*)(bias + 2 * F + f0);
    float4 bo = *(const float4*)(bias + 3 * F + f0);
    float4 c  = *(const float4*)(Cst + (long)pos * F + f0);
    float4 hv, ov4;

#define GATE(comp) { \
        float iv = hsig(zi.comp + bi.comp); \
        float fv = hsig(zf.comp + bf.comp); \
        float gv = tanhf(zg.comp + bg.comp); \
        float og = hsig(zo.comp + bo.comp); \
        float cn = fv * c.comp + iv * gv; \
        float hn = og * tanhf(cn); \
        c.comp = cn; hv.comp = hn; ov4.comp = fmaxf(hn, 0.f); }
    GATE(x) GATE(y) GATE(z) GATE(w)
#undef GATE

    *(float4*)(Cst + (long)pos * F + f0) = c;
    *(float4*)(Hst + (long)pos * F + f0) = hv;
    *(float4*)(Out + (long)b * outBStride + (long)p * F + f0) = ov4;
}

// ---------------------------------------------------------------------------
// Host: 3 layers x 16 timesteps. d_out doubles as the layer-1 sequence buffer
// (fp32, [T,B,H,W,64]); dead once layer 2 finishes. ws: seq2 + h + c + z
// (58.7 MB fp32) + 2.5 MB of pre-split/transposed bf16 weights.
// ---------------------------------------------------------------------------
extern "C" void kernel_launch(void* const* d_in, const int* in_sizes, int n_in,
                              void* d_out, int out_size, void* d_ws, size_t ws_size,
                              hipStream_t stream)
{
    const float* x   = (const float*)d_in[0];
    const float* Wx1 = (const float*)d_in[1];
    const float* Wh1 = (const float*)d_in[2];
    const float* b1  = (const float*)d_in[3];
    const float* Wx2 = (const float*)d_in[4];
    const float* Wh2 = (const float*)d_in[5];
    const float* b2  = (const float*)d_in[6];
    const float* Wx3 = (const float*)d_in[7];
    const float* Wh3 = (const float*)d_in[8];
    const float* b3  = (const float*)d_in[9];
    float* out = (float*)d_out;
    float* ws  = (float*)d_ws;

    const int T = 16, B = 4;
    float* seq2 = ws;                   // 8388608 floats
    float* hbuf = ws + 8388608;         // 1048576
    float* cbuf = ws + 9437184;         // 1048576
    float* zbuf = ws + 10485760;        // 4194304
    unsigned short* wt = (unsigned short*)(ws + 14680064);

    // pre-split weight buffers: [tap][cout][cin] bf16 hi/lo
    struct WSz { const float* W; int C, N; };
    WSz wsrc[6] = {
        { Wx1, 64, 256 }, { Wh1, 64, 256 },
        { Wx2, 64, 128 }, { Wh2, 32, 128 },
        { Wx3, 32, 256 }, { Wh3, 64, 256 },
    };
    unsigned short *Wsp[6][2];
    {
        long off = 0;
        for (int i = 0; i < 6; ++i) {
            long sz = 9L * wsrc[i].C * wsrc[i].N;
            Wsp[i][0] = wt + off; off += sz;
            Wsp[i][1] = wt + off; off += sz;
        }
        for (int i = 0; i < 6; ++i) {
            int total = 9 * wsrc[i].C * wsrc[i].N;
            wsplit<<<(total + 255) / 256, 256, 0, stream>>>(
                wsrc[i].W, wsrc[i].C, wsrc[i].N, Wsp[i][0], Wsp[i][1]);
        }
    }

    struct L {
        int wi;                      // index into Wsp (Wx = wi, Wh = wi+1)
        const float* bias; int Cx, F;
        const float* in0; long inT, inB;
        float* out0; long outT, outB;
    };
    L ls[3] = {
        { 0, b1, 64, 64, x,    (long)HW * 64, (long)T * HW * 64,
          out,  (long)B * HW * 64, (long)HW * 64 },
        { 2, b2, 64, 32, out,  (long)B * HW * 64, (long)HW * 64,
          seq2, (long)B * HW * 32, (long)HW * 32 },
        { 4, b3, 32, 64, seq2, (long)B * HW * 32, (long)HW * 32,
          out,  (long)HW * 64, (long)T * HW * 64 },
    };

    for (int l = 0; l < 3; ++l) {
        const L& P = ls[l];
        int N = 4 * P.F;
        hipMemsetAsync(hbuf, 0, (size_t)B * HW * P.F * sizeof(float), stream);
        hipMemsetAsync(cbuf, 0, (size_t)B * HW * P.F * sizeof(float), stream);
        int lg_nf4 = (P.F == 64) ? 4 : 3;
        int gthreads = B * HW * (P.F / 4);
        for (int t = 0; t < T; ++t) {
            conv_mfma<<<dim3(B * HW / 64, N / 128), 256, 0, stream>>>(
                P.in0 + (long)t * P.inT, P.inB, P.Cx, hbuf, P.F,
                Wsp[P.wi][0], Wsp[P.wi][1], Wsp[P.wi + 1][0], Wsp[P.wi + 1][1],
                zbuf, N);
            lstm_gates<<<gthreads / 256, 256, 0, stream>>>(
                zbuf, P.bias, cbuf, hbuf,
                P.out0 + (long)t * P.outT, P.outB, P.F, N, lg_nf4);
        }
    }
}